// Round 1
// baseline (645.196 us; speedup 1.0000x reference)
//
#include <hip/hip_runtime.h>

#define V 2197000        // 130^3
#define NV4 549250       // V/4
#define TZ 4
#define TY 16
#define TX 16
#define XLZ (TZ+8)       // 12
#define XLY (TY+8)       // 24
#define XLX (TX+8)       // 24
#define DQZ (TZ+4)       // 8
#define DQY (TY+4)       // 20
#define DQX (TX+4)       // 20
#define GTX 9            // ceil(130/16)
#define GTZ 33           // ceil(130/4)
#define NBLK (GTX*GTX*GTZ*2)

// shift tables: 12 channels, (s1 - s2) per dim, values in {0,2,4}
__device__ __constant__ int S1Z[12] = {2,2,2,2,2,4,4,4,2,2,2,2};
__device__ __constant__ int S1Y[12] = {2,0,0,2,2,2,2,2,4,4,4,4};
__device__ __constant__ int S1X[12] = {0,2,2,4,4,2,2,2,2,2,2,2};
__device__ __constant__ int S2Z[12] = {0,0,2,0,2,2,2,2,0,2,2,4};
__device__ __constant__ int S2Y[12] = {2,2,2,2,0,2,0,2,2,2,2,2};
__device__ __constant__ int S2X[12] = {2,2,0,2,2,0,2,4,2,0,4,2};

__device__ __forceinline__ unsigned fkey(float f){
  unsigned u = __float_as_uint(f);
  return (u & 0x80000000u) ? ~u : (u | 0x80000000u);
}
__device__ __forceinline__ float fdecode(unsigned k){
  unsigned u = (k & 0x80000000u) ? (k ^ 0x80000000u) : ~k;
  return __uint_as_float(u);
}

__global__ void init_kernel(unsigned* wsu){
  if (threadIdx.x == 0){
    wsu[0] = 0xFFFFFFFFu;   // min key
    wsu[1] = 0u;            // max key
    ((float*)wsu)[2] = 0.f; // m
  }
}

__global__ __launch_bounds__(256) void minmax_kernel(const float4* __restrict__ x,
                                                     unsigned* wsu, int n4){
  unsigned lmin = 0xFFFFFFFFu, lmax = 0u;
  for (int i = blockIdx.x*256 + threadIdx.x; i < n4; i += gridDim.x*256){
    float4 v = x[i];
    unsigned k0 = fkey(v.x), k1 = fkey(v.y), k2 = fkey(v.z), k3 = fkey(v.w);
    lmin = min(lmin, min(min(k0,k1), min(k2,k3)));
    lmax = max(lmax, max(max(k0,k1), max(k2,k3)));
  }
  #pragma unroll
  for (int off = 32; off > 0; off >>= 1){
    lmin = min(lmin, (unsigned)__shfl_down(lmin, off, 64));
    lmax = max(lmax, (unsigned)__shfl_down(lmax, off, 64));
  }
  __shared__ unsigned smn[4], smx[4];
  if ((threadIdx.x & 63) == 0){ smn[threadIdx.x>>6] = lmin; smx[threadIdx.x>>6] = lmax; }
  __syncthreads();
  if (threadIdx.x == 0){
    unsigned m0 = min(min(smn[0],smn[1]), min(smn[2],smn[3]));
    unsigned m1 = max(max(smx[0],smx[1]), max(smx[2],smx[3]));
    atomicMin(&wsu[0], m0);
    atomicMax(&wsu[1], m1);
  }
}

__global__ __launch_bounds__(256,2) void mind_main(const float* __restrict__ x,
                                                   float* __restrict__ pre,
                                                   float* __restrict__ varr,
                                                   float* __restrict__ bsum,
                                                   const unsigned* __restrict__ wsu){
  __shared__ float XL[XLZ][XLY][XLX];
  __shared__ float DQ[DQZ][DQY][DQX];
  __shared__ float A [DQZ][DQY][TX];
  __shared__ float Bs[DQZ][TY][TX];

  const int tid = threadIdx.x;
  const int b   = blockIdx.z;
  const int p0z = blockIdx.y * TZ;
  const int p0y = (blockIdx.x / GTX) * TY;
  const int p0x = (blockIdx.x % GTX) * TX;

  const float vmin = fdecode(wsu[0]);
  const float vmax = fdecode(wsu[1]);
  const float inv  = 1.0f / (vmax - vmin + 1e-6f);

  const int dloz = max(p0z - 2, 0);
  const int dloy = max(p0y - 2, 0);
  const int dlox = max(p0x - 2, 0);

  // --- load normalized, padded x tile (absolute xp coords q in [dlo, dlo+T+8)) ---
  for (int u = tid; u < XLZ*XLY*XLX; u += 256){
    int uz = u / (XLY*XLX);
    int rem = u - uz*(XLY*XLX);
    int uy = rem / XLX;
    int ux = rem - uy*XLX;
    int qz = dloz + uz, qy = dloy + uy, qx = dlox + ux;
    float v = 0.0f;
    if (qz >= 1 && qz <= 132 && qy >= 1 && qy <= 132 && qx >= 1 && qx <= 132){
      int iz = min(max(qz-3,0),127);
      int iy = min(max(qy-3,0),127);
      int ix = min(max(qx-3,0),127);
      v = (x[((b*128 + iz)*128 + iy)*128 + ix] - vmin) * inv;
    }
    ((float*)XL)[u] = v;
  }
  __syncthreads();

  float acc[12][TZ];
  const int oyT = tid >> 4;
  const int oxT = tid & 15;

  #pragma unroll
  for (int c = 0; c < 12; ++c){
    const int s1z = S1Z[c], s1y = S1Y[c], s1x = S1X[c];
    const int s2z = S2Z[c], s2y = S2Y[c], s2x = S2X[c];
    // diff^2 tile over edge-clamped diff positions
    for (int u = tid; u < DQZ*DQY*DQX; u += 256){
      int tz = u / (DQY*DQX);
      int rem = u - tz*(DQY*DQX);
      int ty = rem / DQX;
      int tx = rem - ty*DQX;
      int ez = max(min(p0z - 2 + tz, 129), 0) - dloz;
      int ey = max(min(p0y - 2 + ty, 129), 0) - dloy;
      int ex = max(min(p0x - 2 + tx, 129), 0) - dlox;
      float d = XL[ez+s1z][ey+s1y][ex+s1x] - XL[ez+s2z][ey+s2y][ex+s2x];
      ((float*)DQ)[u] = d*d;
    }
    __syncthreads();
    // x-pass
    for (int u = tid; u < DQZ*DQY*TX; u += 256){
      int tz = u / (DQY*TX);
      int rem = u - tz*(DQY*TX);
      int ty = rem / TX;
      int ox = rem - ty*TX;
      A[tz][ty][ox] = DQ[tz][ty][ox] + DQ[tz][ty][ox+1] + DQ[tz][ty][ox+2]
                    + DQ[tz][ty][ox+3] + DQ[tz][ty][ox+4];
    }
    __syncthreads();
    // y-pass
    for (int u = tid; u < DQZ*TY*TX; u += 256){
      int tz = u / (TY*TX);
      int rem = u - tz*(TY*TX);
      int oy = rem / TX;
      int ox = rem - oy*TX;
      Bs[tz][oy][ox] = A[tz][oy][ox] + A[tz][oy+1][ox] + A[tz][oy+2][ox]
                     + A[tz][oy+3][ox] + A[tz][oy+4][ox];
    }
    __syncthreads();
    // z-pass into registers
    #pragma unroll
    for (int k = 0; k < TZ; ++k){
      acc[c][k] = (Bs[k][oyT][oxT] + Bs[k+1][oyT][oxT] + Bs[k+2][oyT][oxT]
                 + Bs[k+3][oyT][oxT] + Bs[k+4][oyT][oxT]) * (1.0f/125.0f);
    }
    __syncthreads();
  }

  // --- per-voxel min/mean, write pre = ssd - min, var ---
  const int oyv = p0y + oyT;
  const int oxv = p0x + oxT;
  float vlocal = 0.0f;
  if (oyv < 130 && oxv < 130){
    #pragma unroll
    for (int k = 0; k < TZ; ++k){
      const int ozv = p0z + k;
      if (ozv < 130){
        float mn = acc[0][k], sm = acc[0][k];
        #pragma unroll
        for (int c = 1; c < 12; ++c){ mn = fminf(mn, acc[c][k]); sm += acc[c][k]; }
        const float mv = sm * (1.0f/12.0f) - mn;
        const int vox = ozv*16900 + oyv*130 + oxv;
        varr[b*V + vox] = mv;
        vlocal += mv;
        const int obase = b*12*V + vox;
        #pragma unroll
        for (int c = 0; c < 12; ++c) pre[obase + c*V] = acc[c][k] - mn;
      }
    }
  }

  // deterministic per-block partial sum
  #pragma unroll
  for (int off = 32; off > 0; off >>= 1) vlocal += __shfl_down(vlocal, off, 64);
  __shared__ float wred[4];
  if ((tid & 63) == 0) wred[tid>>6] = vlocal;
  __syncthreads();
  if (tid == 0){
    const int blin = (blockIdx.z*gridDim.y + blockIdx.y)*gridDim.x + blockIdx.x;
    bsum[blin] = wred[0] + wred[1] + wred[2] + wred[3];
  }
}

__global__ __launch_bounds__(256) void reduce_bsum(const float* __restrict__ bsum, float* wsf){
  __shared__ float sm[256];
  float s = 0.0f;
  for (int i = threadIdx.x; i < NBLK; i += 256) s += bsum[i];
  sm[threadIdx.x] = s;
  __syncthreads();
  for (int w = 128; w > 0; w >>= 1){
    if (threadIdx.x < w) sm[threadIdx.x] += sm[threadIdx.x + w];
    __syncthreads();
  }
  if (threadIdx.x == 0) wsf[2] = sm[0] * (1.0f/4394000.0f);
}

__global__ __launch_bounds__(256) void final_kernel(float* __restrict__ out,
                                                    const float* __restrict__ varr,
                                                    const float* __restrict__ wsf){
  const int q = blockIdx.x*256 + threadIdx.x;
  if (q >= 2*NV4) return;
  const float m = wsf[2];
  const float lo = m * 0.001f, hi = m * 1000.0f;
  const int b  = q / NV4;
  const int vq = q - b*NV4;
  float4 vv = reinterpret_cast<const float4*>(varr)[q];
  const float r0 = 1.0f / fminf(fmaxf(vv.x, lo), hi);
  const float r1 = 1.0f / fminf(fmaxf(vv.y, lo), hi);
  const float r2 = 1.0f / fminf(fmaxf(vv.z, lo), hi);
  const float r3 = 1.0f / fminf(fmaxf(vv.w, lo), hi);
  const int ob = (b*12)*NV4 + vq;
  #pragma unroll
  for (int c = 0; c < 12; ++c){
    float4 p = reinterpret_cast<float4*>(out)[ob + c*NV4];
    p.x = __expf(-p.x * r0);
    p.y = __expf(-p.y * r1);
    p.z = __expf(-p.z * r2);
    p.w = __expf(-p.w * r3);
    reinterpret_cast<float4*>(out)[ob + c*NV4] = p;
  }
}

extern "C" void kernel_launch(void* const* d_in, const int* in_sizes, int n_in,
                              void* d_out, int out_size, void* d_ws, size_t ws_size,
                              hipStream_t stream){
  (void)in_sizes; (void)n_in; (void)out_size; (void)ws_size;
  const float* x = (const float*)d_in[0];
  float* out = (float*)d_out;
  unsigned* wsu = (unsigned*)d_ws;
  float* wsf = (float*)d_ws;
  float* varr = (float*)((char*)d_ws + 64);
  float* bsum = (float*)((char*)d_ws + 64 + (size_t)2*V*sizeof(float));

  hipLaunchKernelGGL(init_kernel, dim3(1), dim3(64), 0, stream, wsu);
  hipLaunchKernelGGL(minmax_kernel, dim3(1024), dim3(256), 0, stream,
                     (const float4*)x, wsu, 1048576);
  hipLaunchKernelGGL(mind_main, dim3(GTX*GTX, GTZ, 2), dim3(256), 0, stream,
                     x, out, varr, bsum, wsu);
  hipLaunchKernelGGL(reduce_bsum, dim3(1), dim3(256), 0, stream, bsum, wsf);
  hipLaunchKernelGGL(final_kernel, dim3((2*NV4+255)/256), dim3(256), 0, stream,
                     out, varr, wsf);
}

// Round 2
// 241.431 us; speedup vs baseline: 2.6724x; 2.6724x over previous
//
#include <hip/hip_runtime.h>
#include <type_traits>

#define V 2197000        // 130^3
#define NV4 549250       // V/4
#define VPL 16900        // 130*130
#define NBLK 2106        // 81*13*2

// ---------------- main fused kernel ----------------
// Tile: 10(z) x 16(y) x 16(x) outputs per block. 256 threads.
// LDS: XL = xp tile 18x24 rows x 28-pad floats (conflict-free stride),
//      A4 = x-filtered diff^2, XOR-swizzled float4 quads [14*20 rows][4],
//      Bs = xy-filtered [14][16][16].
__global__ __launch_bounds__(256,2) void mind_main(const float* __restrict__ x,
                                                   float* __restrict__ pre,
                                                   float* __restrict__ bsum){
  __shared__ float XL[18*24*28];
  __shared__ float4 A4[14*20*4];
  __shared__ float Bs[14*16*16];
  __shared__ float wred[4];

  const int tid = threadIdx.x;
  const int bxg = blockIdx.x % 9;
  const int byg = blockIdx.x / 9;
  const int p0x = bxg*16, p0y = byg*16, p0z = blockIdx.y*10;
  const int b = blockIdx.z;
  const int z0 = max(p0z-2,0), y0 = max(p0y-2,0), x0 = max(p0x-2,0);

  // ---- fill XL with raw xp values (zero ring at xp index 0/133, edge-replicate inside) ----
  const float* xb = x + b*128*128*128;
  for (int u = tid; u < 18*24*24; u += 256){
    int uz = u / 576;
    int rem = u - uz*576;
    int uy = rem / 24;
    int ux = rem - uy*24;
    int qz = z0+uz, qy = y0+uy, qx = x0+ux;
    float v = 0.f;
    if (qz>=1 && qz<=132 && qy>=1 && qy<=132 && qx>=1 && qx<=132){
      int iz = min(max(qz-3,0),127);
      int iy = min(max(qy-3,0),127);
      int ix = min(max(qx-3,0),127);
      v = xb[(iz*128+iy)*128+ix];
    }
    XL[(uz*24+uy)*28 + ux] = v;
  }

  // ---- per-thread precompute (channel-independent) ----
  int rb[2], wrow[2];
  #pragma unroll
  for (int r=0;r<2;++r){
    int u = tid + (r<<8); if (u > 279) u = 279;
    int tz = u/20, ty = u - tz*20;
    int ez = min(max(p0z-2+tz,0),129);
    int ey = min(max(p0y-2+ty,0),129);
    rb[r] = ((ez-z0)*24 + (ey-y0))*28;
    wrow[r] = tz*20 + ty;
  }
  const int nrows = (tid < 24) ? 2 : 1;

  int yrow[4], yq[4], ywi[4];
  #pragma unroll
  for (int k=0;k<4;++k){
    int g = tid + (k<<8); if (g >= 896) g = 0;
    int tz = g>>6, oy = (g>>2)&15, oxg = g&3;
    yrow[k] = tz*20 + oy;
    yq[k]   = oxg;
    ywi[k]  = (tz*16+oy)*16 + oxg*4;
  }
  const int ng = (tid < 128) ? 4 : 3;

  const int oyT = tid>>4, oxT = tid&15;
  const int zr = oyT*16 + oxT;
  const int oyv = p0y + oyT, oxv = p0x + oxT;
  const bool valid = (oyv < 130) && (oxv < 130);
  float* gp = pre + ((b*12)*V + p0z*VPL + oyv*130 + oxv);

  float rmin[10], rsum[10];
  #pragma unroll
  for (int k=0;k<10;++k){ rmin[k] = 0.f; rsum[k] = 0.f; }

  __syncthreads();

  // ---- per-channel processing; template instantiation guarantees constant folding ----
  auto do_channel = [&](auto CC){
    constexpr int c = decltype(CC)::value;
    constexpr int S1Z[12] = {2,2,2,2,2,4,4,4,2,2,2,2};
    constexpr int S1Y[12] = {2,0,0,2,2,2,2,2,4,4,4,4};
    constexpr int S1X[12] = {0,2,2,4,4,2,2,2,2,2,2,2};
    constexpr int S2Z[12] = {0,0,2,0,2,2,2,2,0,2,2,4};
    constexpr int S2Y[12] = {2,2,2,2,0,2,0,2,2,2,2,2};
    constexpr int S2X[12] = {2,2,0,2,2,0,2,4,2,0,4,2};
    constexpr int o1 = S1Z[c]*(24*28) + S1Y[c]*28;
    constexpr int o2 = S2Z[c]*(24*28) + S2Y[c]*28;
    constexpr int s1x = S1X[c], s2x = S2X[c];

    // A stage: fused diff^2 + 5-tap x-filter, whole row in registers
    #pragma unroll
    for (int r=0;r<2;++r){
      if (r < nrows){
        float rr1[24], rr2[24];
        const float4* q1 = (const float4*)(XL + rb[r] + o1);
        const float4* q2 = (const float4*)(XL + rb[r] + o2);
        #pragma unroll
        for (int j=0;j<6;++j){
          float4 a = q1[j];
          rr1[4*j]=a.x; rr1[4*j+1]=a.y; rr1[4*j+2]=a.z; rr1[4*j+3]=a.w;
          float4 bb = q2[j];
          rr2[4*j]=bb.x; rr2[4*j+1]=bb.y; rr2[4*j+2]=bb.z; rr2[4*j+3]=bb.w;
        }
        float dd[20];
        #pragma unroll
        for (int t=0;t<20;++t){
          float d = rr1[t+s1x] - rr2[t+s2x];
          dd[t] = d*d;
        }
        float W[16];
        W[0] = dd[0]+dd[1]+dd[2]+dd[3]+dd[4];
        #pragma unroll
        for (int j=1;j<16;++j) W[j] = W[j-1] + dd[j+4] - dd[j-1];
        float Ao[16];
        if (bxg == 0){           // left x-edge: window positions clamp to 0
          Ao[0] = W[0] + 2.f*dd[0] - dd[3] - dd[4];   // 3d0+d1+d2
          Ao[1] = W[0] + dd[0] - dd[4];               // 2d0+d1+d2+d3
          #pragma unroll
          for (int j=2;j<16;++j) Ao[j] = W[j-2];
        } else if (bxg == 8){    // right x-edge: only outputs 0,1 are real
          Ao[0] = W[0] + dd[3] - dd[4];               // d0+d1+d2+2d3
          Ao[1] = W[0] - dd[0] + 2.f*dd[3] - dd[4];   // d1+d2+3d3
          #pragma unroll
          for (int j=2;j<16;++j) Ao[j] = W[j-2];      // finite garbage, never stored
        } else {
          #pragma unroll
          for (int j=0;j<16;++j) Ao[j] = W[j];
        }
        const int wr = wrow[r];
        #pragma unroll
        for (int q=0;q<4;++q){
          A4[wr*4 + (q ^ (wr&3))] = make_float4(Ao[4*q],Ao[4*q+1],Ao[4*q+2],Ao[4*q+3]);
        }
      }
    }
    __syncthreads();
    // y stage: 5-tap along y, float4 wide
    #pragma unroll
    for (int k=0;k<4;++k){
      if (k < ng){
        float4 s = make_float4(0.f,0.f,0.f,0.f);
        #pragma unroll
        for (int dy=0;dy<5;++dy){
          int row = yrow[k] + dy;
          float4 a = A4[row*4 + (yq[k] ^ (row&3))];
          s.x += a.x; s.y += a.y; s.z += a.z; s.w += a.w;
        }
        *(float4*)(Bs + ywi[k]) = s;
      }
    }
    __syncthreads();
    // z stage: sliding 5-window along z, store raw ssd, keep running min/sum
    float Bv[14];
    #pragma unroll
    for (int k=0;k<14;++k) Bv[k] = Bs[zr + k*256];
    float S = Bv[0]+Bv[1]+Bv[2]+Bv[3]+Bv[4];
    #pragma unroll
    for (int k=0;k<10;++k){
      if (valid) gp[c*V + k*VPL] = S;
      if (c==0){ rmin[k] = S; rsum[k] = S; }
      else     { rmin[k] = fminf(rmin[k], S); rsum[k] += S; }
      if (k<9) S += Bv[k+5] - Bv[k];
    }
    // no barrier needed: next channel's A stage touches A4/XL only; the
    // barrier after its A stage orders our Bs reads vs next y writes.
  };
  do_channel(std::integral_constant<int,0>{});
  do_channel(std::integral_constant<int,1>{});
  do_channel(std::integral_constant<int,2>{});
  do_channel(std::integral_constant<int,3>{});
  do_channel(std::integral_constant<int,4>{});
  do_channel(std::integral_constant<int,5>{});
  do_channel(std::integral_constant<int,6>{});
  do_channel(std::integral_constant<int,7>{});
  do_channel(std::integral_constant<int,8>{});
  do_channel(std::integral_constant<int,9>{});
  do_channel(std::integral_constant<int,10>{});
  do_channel(std::integral_constant<int,11>{});

  // ---- partial sum of mind_var (raw scale) ----
  float vl = 0.f;
  if (valid){
    #pragma unroll
    for (int k=0;k<10;++k) vl += rsum[k]*(1.0f/12.0f) - rmin[k];
  }
  #pragma unroll
  for (int off=32; off>0; off>>=1) vl += __shfl_down(vl, off, 64);
  if ((tid&63)==0) wred[tid>>6] = vl;
  __syncthreads();
  if (tid==0){
    int blin = (blockIdx.z*13 + blockIdx.y)*81 + blockIdx.x;
    bsum[blin] = wred[0]+wred[1]+wred[2]+wred[3];
  }
}

// ---------------- deterministic reduce for m ----------------
__global__ __launch_bounds__(256) void reduce_bsum(const float* __restrict__ bsum, float* wsf){
  __shared__ float sm[256];
  float s = 0.f;
  for (int i = threadIdx.x; i < NBLK; i += 256) s += bsum[i];
  sm[threadIdx.x] = s;
  __syncthreads();
  for (int w = 128; w > 0; w >>= 1){
    if (threadIdx.x < w) sm[threadIdx.x] += sm[threadIdx.x + w];
    __syncthreads();
  }
  if (threadIdx.x == 0) wsf[2] = sm[0] * (1.0f/4394000.0f);
}

// ---------------- finalize: min/mean/clamp/exp in-place on raw ssd ----------------
__global__ __launch_bounds__(256) void final_kernel(float* __restrict__ out,
                                                    const float* __restrict__ wsf){
  const int q = blockIdx.x*256 + threadIdx.x;
  if (q >= 2*NV4) return;
  const float m = wsf[2];
  const float lo = m*0.001f, hi = m*1000.f;
  const int b = q / NV4;
  const int vq = q - b*NV4;
  float4* o4 = (float4*)out;
  const int ob = b*12*NV4 + vq;
  float4 p[12];
  #pragma unroll
  for (int c=0;c<12;++c) p[c] = o4[ob + c*NV4];
  float4 mn = p[0], sm = p[0];
  #pragma unroll
  for (int c=1;c<12;++c){
    mn.x = fminf(mn.x,p[c].x); mn.y = fminf(mn.y,p[c].y);
    mn.z = fminf(mn.z,p[c].z); mn.w = fminf(mn.w,p[c].w);
    sm.x += p[c].x; sm.y += p[c].y; sm.z += p[c].z; sm.w += p[c].w;
  }
  const float rx = 1.f/fminf(fmaxf(sm.x*(1.f/12.f)-mn.x, lo), hi);
  const float ry = 1.f/fminf(fmaxf(sm.y*(1.f/12.f)-mn.y, lo), hi);
  const float rz = 1.f/fminf(fmaxf(sm.z*(1.f/12.f)-mn.z, lo), hi);
  const float rw = 1.f/fminf(fmaxf(sm.w*(1.f/12.f)-mn.w, lo), hi);
  #pragma unroll
  for (int c=0;c<12;++c){
    float4 e;
    e.x = __expf(-(p[c].x-mn.x)*rx);
    e.y = __expf(-(p[c].y-mn.y)*ry);
    e.z = __expf(-(p[c].z-mn.z)*rz);
    e.w = __expf(-(p[c].w-mn.w)*rw);
    o4[ob + c*NV4] = e;
  }
}

extern "C" void kernel_launch(void* const* d_in, const int* in_sizes, int n_in,
                              void* d_out, int out_size, void* d_ws, size_t ws_size,
                              hipStream_t stream){
  (void)in_sizes; (void)n_in; (void)out_size; (void)ws_size;
  const float* x = (const float*)d_in[0];
  float* out = (float*)d_out;
  float* wsf = (float*)d_ws;
  float* bsum = (float*)((char*)d_ws + 64);

  hipLaunchKernelGGL(mind_main, dim3(81,13,2), dim3(256), 0, stream, x, out, bsum);
  hipLaunchKernelGGL(reduce_bsum, dim3(1), dim3(256), 0, stream, bsum, wsf);
  hipLaunchKernelGGL(final_kernel, dim3((2*NV4+255)/256), dim3(256), 0, stream, out, wsf);
}

// Round 3
// 226.504 us; speedup vs baseline: 2.8485x; 1.0659x over previous
//
#include <hip/hip_runtime.h>

#define V 2197000        // 130^3
#define NV4 549250       // V/4
#define VPL 16900        // 130*130
#define TX 16
#define TY 13
#define TZ 10
#define DQY 17           // TY+4
#define DQZ 14           // TZ+4
#define NROWS 238        // DQZ*DQY
#define XLY 21           // TY+8
#define XLZ 18           // TZ+8
#define XLP 28           // padded LDS row stride (floats), conflict-optimal for b128
#define A4P 20           // A4 row stride (floats): 8-way writes, ~free reads
#define NXY 90           // 9 x-tiles * 10 y-tiles
#define NWG 2340         // NXY*13*2

// ---- A stage: fused diff^2 + 5-tap x-filter, pure VALU from register rows ----
template<int S1X, int S2X>
__device__ __forceinline__ void aphase(const float (&r1)[24], const float (&r2)[24],
                                       float* __restrict__ buf, int wr, int bxg, bool arow){
  if (!arow) return;
  float dd[20];
  #pragma unroll
  for (int t=0;t<20;++t){ float d = r1[t+S1X]-r2[t+S2X]; dd[t]=d*d; }
  float W[16];
  W[0]=dd[0]+dd[1]+dd[2]+dd[3]+dd[4];
  #pragma unroll
  for (int j=1;j<16;++j) W[j]=W[j-1]+dd[j+4]-dd[j-1];
  float Ao[16];
  if (bxg==0){           // left x-edge: window positions clamp to 0
    Ao[0]=W[0]+2.f*dd[0]-dd[3]-dd[4];
    Ao[1]=W[0]+dd[0]-dd[4];
    #pragma unroll
    for(int j=2;j<16;++j) Ao[j]=W[j-2];
  } else if (bxg==8){    // right x-edge: only outputs 0,1 real; rest finite garbage
    Ao[0]=W[0]+dd[3]-dd[4];
    Ao[1]=W[0]-dd[0]+2.f*dd[3]-dd[4];
    #pragma unroll
    for(int j=2;j<16;++j) Ao[j]=W[j-2];
  } else {
    #pragma unroll
    for(int j=0;j<16;++j) Ao[j]=W[j];
  }
  float4* bw = (float4*)(buf + wr*A4P);
  #pragma unroll
  for (int j=0;j<4;++j)
    bw[j] = make_float4(Ao[4*j],Ao[4*j+1],Ao[4*j+2],Ao[4*j+3]);
}

// ---- merged Y+Z stage: 5-tap y (70 imm-offset b32 reads) + sliding-z, store raw ssd ----
__device__ __forceinline__ void yzphase(const float* __restrict__ buf, int oyT, int oxT,
                                        bool yzact, bool valid, float* __restrict__ gp,
                                        float (&rmin)[10], float (&rsum)[10],
                                        bool first, int cV){
  if (!yzact) return;
  const float* bp = buf + oyT*A4P + oxT;
  float By[14];
  #pragma unroll
  for (int z=0;z<14;++z){
    By[z] = bp[(z*17+0)*A4P] + bp[(z*17+1)*A4P] + bp[(z*17+2)*A4P]
          + bp[(z*17+3)*A4P] + bp[(z*17+4)*A4P];
  }
  float S = By[0]+By[1]+By[2]+By[3]+By[4];
  #pragma unroll
  for (int k=0;k<10;++k){
    if (valid) gp[cV + k*VPL] = S;
    if (first){ rmin[k]=S; rsum[k]=S; }
    else      { rmin[k]=fminf(rmin[k],S); rsum[k]+=S; }
    if (k<9) S += By[k+5]-By[k];
  }
}

__global__ __launch_bounds__(256,2) void mind_main(const float* __restrict__ x,
                                                   float* __restrict__ pre,
                                                   float* __restrict__ bsum){
  __shared__ float XL[XLZ*XLY*XLP];
  __shared__ float A4[2][NROWS*A4P];
  __shared__ float wred[4];

  const int tid = threadIdx.x;
  // bijective XCD-chunk swizzle (nwg=2340: q=292, r=4) — consecutive tiles on same XCD
  const int orig = blockIdx.x;
  const int xcd = orig & 7, posi = orig >> 3;
  const int t = (xcd < 4) ? xcd*293 + posi : 1172 + (xcd-4)*292 + posi;
  const int xyb = t % NXY;
  const int rest = t / NXY;
  const int zb = rest % 13;
  const int b  = rest / 13;
  const int bxg = xyb % 9, byg = xyb / 9;
  const int p0x = bxg*16, p0y = byg*13, p0z = zb*10;
  const int z0 = max(p0z-2,0), y0 = max(p0y-2,0), x0 = max(p0x-2,0);

  // ---- fill XL with raw xp values (zero ring at xp 0/133, edge-replicate inside) ----
  const float* xb = x + b*2097152;
  for (int u = tid; u < XLZ*XLY*24; u += 256){
    int uz = u / (XLY*24);
    int rem = u - uz*(XLY*24);
    int uy = rem / 24;
    int ux = rem - uy*24;
    int qz = z0+uz, qy = y0+uy, qx = x0+ux;
    float v = 0.f;
    if (qz>=1 && qz<=132 && qy>=1 && qy<=132 && qx>=1 && qx<=132){
      int iz = min(max(qz-3,0),127);
      int iy = min(max(qy-3,0),127);
      int ix = min(max(qx-3,0),127);
      v = xb[(iz<<14)+(iy<<7)+ix];
    }
    XL[(uz*XLY+uy)*XLP + ux] = v;
  }

  // ---- per-thread row geometry ----
  const bool arow = tid < NROWS;
  int rbase;
  {
    int tt = arow ? tid : 0;
    int tz = tt / DQY, ty = tt - tz*DQY;
    int ez = min(max(p0z-2+tz,0),129);
    int ey = min(max(p0y-2+ty,0),129);
    rbase = ((ez - z0)*XLY + (ey - y0))*XLP;
  }
  const int wr = tid;

  const int oyT = tid>>4, oxT = tid&15;
  const bool yzact = tid < TY*TX;           // 208
  const bool valid = yzact && (p0x + oxT < 130);
  float* gp = pre + (b*12*V + p0z*VPL + (p0y+oyT)*130 + (p0x+oxT));
  float rmin[10], rsum[10];

  __syncthreads();

  // ---- load the 5 distinct source rows into registers (once, for all 12 channels) ----
  // sources (sz,sy): A(2,2) B(2,0) C(4,2) D(2,4) E(0,2)
  float rA[24],rB[24],rC[24],rD[24],rE[24];
  if (arow){
    const float4* qA = (const float4*)(XL + rbase + (2*XLY+2)*XLP);
    const float4* qB = (const float4*)(XL + rbase + (2*XLY+0)*XLP);
    const float4* qC = (const float4*)(XL + rbase + (4*XLY+2)*XLP);
    const float4* qD = (const float4*)(XL + rbase + (2*XLY+4)*XLP);
    const float4* qE = (const float4*)(XL + rbase + (0*XLY+2)*XLP);
    #pragma unroll
    for (int j=0;j<6;++j){
      float4 v;
      v=qA[j]; rA[4*j]=v.x; rA[4*j+1]=v.y; rA[4*j+2]=v.z; rA[4*j+3]=v.w;
      v=qB[j]; rB[4*j]=v.x; rB[4*j+1]=v.y; rB[4*j+2]=v.z; rB[4*j+3]=v.w;
      v=qC[j]; rC[4*j]=v.x; rC[4*j+1]=v.y; rC[4*j+2]=v.z; rC[4*j+3]=v.w;
      v=qD[j]; rD[4*j]=v.x; rD[4*j+1]=v.y; rD[4*j+2]=v.z; rD[4*j+3]=v.w;
      v=qE[j]; rE[4*j]=v.x; rE[4*j+1]=v.y; rE[4*j+2]=v.z; rE[4*j+3]=v.w;
    }
  }

  // ---- 12 channels, double-buffered A4, 1 barrier per channel ----
  aphase<0,2>(rA,rE,A4[0],wr,bxg,arow);                       // c0
  __syncthreads();
  yzphase(A4[0],oyT,oxT,yzact,valid,gp,rmin,rsum,true , 0*V);
  aphase<2,2>(rB,rE,A4[1],wr,bxg,arow);                       // c1
  __syncthreads();
  yzphase(A4[1],oyT,oxT,yzact,valid,gp,rmin,rsum,false, 1*V);
  aphase<2,0>(rB,rA,A4[0],wr,bxg,arow);                       // c2
  __syncthreads();
  yzphase(A4[0],oyT,oxT,yzact,valid,gp,rmin,rsum,false, 2*V);
  aphase<4,2>(rA,rE,A4[1],wr,bxg,arow);                       // c3
  __syncthreads();
  yzphase(A4[1],oyT,oxT,yzact,valid,gp,rmin,rsum,false, 3*V);
  aphase<4,2>(rA,rB,A4[0],wr,bxg,arow);                       // c4
  __syncthreads();
  yzphase(A4[0],oyT,oxT,yzact,valid,gp,rmin,rsum,false, 4*V);
  aphase<2,0>(rC,rA,A4[1],wr,bxg,arow);                       // c5
  __syncthreads();
  yzphase(A4[1],oyT,oxT,yzact,valid,gp,rmin,rsum,false, 5*V);
  aphase<2,2>(rC,rB,A4[0],wr,bxg,arow);                       // c6
  __syncthreads();
  yzphase(A4[0],oyT,oxT,yzact,valid,gp,rmin,rsum,false, 6*V);
  aphase<2,4>(rC,rA,A4[1],wr,bxg,arow);                       // c7
  __syncthreads();
  yzphase(A4[1],oyT,oxT,yzact,valid,gp,rmin,rsum,false, 7*V);
  aphase<2,2>(rD,rE,A4[0],wr,bxg,arow);                       // c8
  __syncthreads();
  yzphase(A4[0],oyT,oxT,yzact,valid,gp,rmin,rsum,false, 8*V);
  aphase<2,0>(rD,rA,A4[1],wr,bxg,arow);                       // c9
  __syncthreads();
  yzphase(A4[1],oyT,oxT,yzact,valid,gp,rmin,rsum,false, 9*V);
  aphase<2,4>(rD,rA,A4[0],wr,bxg,arow);                       // c10
  __syncthreads();
  yzphase(A4[0],oyT,oxT,yzact,valid,gp,rmin,rsum,false,10*V);
  aphase<2,2>(rD,rC,A4[1],wr,bxg,arow);                       // c11
  __syncthreads();
  yzphase(A4[1],oyT,oxT,yzact,valid,gp,rmin,rsum,false,11*V);

  // ---- deterministic partial sum of mind_var (raw scale) ----
  float vl = 0.f;
  if (valid){
    #pragma unroll
    for (int k=0;k<10;++k) vl += rsum[k]*(1.0f/12.0f) - rmin[k];
  }
  #pragma unroll
  for (int off=32; off>0; off>>=1) vl += __shfl_down(vl, off, 64);
  if ((tid&63)==0) wred[tid>>6] = vl;
  __syncthreads();
  if (tid==0) bsum[orig] = wred[0]+wred[1]+wred[2]+wred[3];
}

// ---------------- deterministic reduce for m ----------------
__global__ __launch_bounds__(256) void reduce_bsum(const float* __restrict__ bsum, float* wsf){
  __shared__ float sm[256];
  float s = 0.f;
  for (int i = threadIdx.x; i < NWG; i += 256) s += bsum[i];
  sm[threadIdx.x] = s;
  __syncthreads();
  for (int w = 128; w > 0; w >>= 1){
    if (threadIdx.x < w) sm[threadIdx.x] += sm[threadIdx.x + w];
    __syncthreads();
  }
  if (threadIdx.x == 0) wsf[2] = sm[0] * (1.0f/4394000.0f);
}

// ---------------- finalize: min/mean/clamp/exp in-place on raw ssd ----------------
__global__ __launch_bounds__(256) void final_kernel(float* __restrict__ out,
                                                    const float* __restrict__ wsf){
  const int q = blockIdx.x*256 + threadIdx.x;
  if (q >= 2*NV4) return;
  const float m = wsf[2];
  const float lo = m*0.001f, hi = m*1000.f;
  const int b = q / NV4;
  const int vq = q - b*NV4;
  float4* o4 = (float4*)out;
  const int ob = b*12*NV4 + vq;
  float4 p[12];
  #pragma unroll
  for (int c=0;c<12;++c) p[c] = o4[ob + c*NV4];
  float4 mn = p[0], sm = p[0];
  #pragma unroll
  for (int c=1;c<12;++c){
    mn.x = fminf(mn.x,p[c].x); mn.y = fminf(mn.y,p[c].y);
    mn.z = fminf(mn.z,p[c].z); mn.w = fminf(mn.w,p[c].w);
    sm.x += p[c].x; sm.y += p[c].y; sm.z += p[c].z; sm.w += p[c].w;
  }
  const float rx = 1.f/fminf(fmaxf(sm.x*(1.f/12.f)-mn.x, lo), hi);
  const float ry = 1.f/fminf(fmaxf(sm.y*(1.f/12.f)-mn.y, lo), hi);
  const float rz = 1.f/fminf(fmaxf(sm.z*(1.f/12.f)-mn.z, lo), hi);
  const float rw = 1.f/fminf(fmaxf(sm.w*(1.f/12.f)-mn.w, lo), hi);
  #pragma unroll
  for (int c=0;c<12;++c){
    float4 e;
    e.x = __expf(-(p[c].x-mn.x)*rx);
    e.y = __expf(-(p[c].y-mn.y)*ry);
    e.z = __expf(-(p[c].z-mn.z)*rz);
    e.w = __expf(-(p[c].w-mn.w)*rw);
    o4[ob + c*NV4] = e;
  }
}

extern "C" void kernel_launch(void* const* d_in, const int* in_sizes, int n_in,
                              void* d_out, int out_size, void* d_ws, size_t ws_size,
                              hipStream_t stream){
  (void)in_sizes; (void)n_in; (void)out_size; (void)ws_size;
  const float* x = (const float*)d_in[0];
  float* out = (float*)d_out;
  float* wsf = (float*)d_ws;
  float* bsum = (float*)((char*)d_ws + 64);

  hipLaunchKernelGGL(mind_main, dim3(NWG), dim3(256), 0, stream, x, out, bsum);
  hipLaunchKernelGGL(reduce_bsum, dim3(1), dim3(256), 0, stream, bsum, wsf);
  hipLaunchKernelGGL(final_kernel, dim3((2*NV4+255)/256), dim3(256), 0, stream, out, wsf);
}